// Round 1
// baseline (876.919 us; speedup 1.0000x reference)
//
#include <hip/hip_runtime.h>
#include <hip/hip_bf16.h>

#define S_LEN 2048
#define DKC   64
#define QBLK  64
#define NEGV  (-1e9f)

typedef __attribute__((ext_vector_type(8))) short short8v;
typedef __attribute__((ext_vector_type(4))) float f32x4;

__device__ __forceinline__ short f2bf(float f){
  unsigned u = __builtin_bit_cast(unsigned, f);
  u += 0x7fffu + ((u >> 16) & 1u);          // RNE to bf16
  return (short)(u >> 16);
}

// swizzled element index for a [rows][64] bf16 LDS tile (128B rows)
__device__ __forceinline__ int swz(int row, int col){
  return (row * 64 + col) ^ ((row & 7) << 3);
}

// stage a 64x64 fp32 tile (row-major, ld=64) -> bf16 LDS [64][64] swizzled
__device__ __forceinline__ void stage_rows_bf16(short* dst, const float* src, int tid){
  const int r  = tid >> 2;
  const int c0 = (tid & 3) * 16;
  const float* p = src + (size_t)r * DKC + c0;
  float4 a0 = *(const float4*)(p);
  float4 a1 = *(const float4*)(p + 4);
  float4 a2 = *(const float4*)(p + 8);
  float4 a3 = *(const float4*)(p + 12);
  short8v s0, s1;
  s0[0]=f2bf(a0.x); s0[1]=f2bf(a0.y); s0[2]=f2bf(a0.z); s0[3]=f2bf(a0.w);
  s0[4]=f2bf(a1.x); s0[5]=f2bf(a1.y); s0[6]=f2bf(a1.z); s0[7]=f2bf(a1.w);
  s1[0]=f2bf(a2.x); s1[1]=f2bf(a2.y); s1[2]=f2bf(a2.z); s1[3]=f2bf(a2.w);
  s1[4]=f2bf(a3.x); s1[5]=f2bf(a3.y); s1[6]=f2bf(a3.z); s1[7]=f2bf(a3.w);
  *(short8v*)&dst[swz(r, c0)]     = s0;
  *(short8v*)&dst[swz(r, c0 + 8)] = s1;
}

// stage a 64x64 fp32 tile TRANSPOSED -> bf16 LDS [d=64][k=64] swizzled
__device__ __forceinline__ void stage_vT_bf16(short* dst, const float* src, int tid){
  const int k  = tid >> 4;         // 0..15
  const int d0 = (tid & 15) * 4;   // 0..60
  #pragma unroll
  for (int i = 0; i < 4; ++i){
    const int kk = k + 16 * i;
    const float4 v = *(const float4*)(src + (size_t)kk * DKC + d0);
    dst[swz(d0 + 0, kk)] = f2bf(v.x);
    dst[swz(d0 + 1, kk)] = f2bf(v.y);
    dst[swz(d0 + 2, kk)] = f2bf(v.z);
    dst[swz(d0 + 3, kk)] = f2bf(v.w);
  }
}

__global__ void maskpack_kernel(const int* __restrict__ mask, unsigned long long* __restrict__ bits){
  const int w    = blockIdx.x * 4 + (threadIdx.x >> 6);  // global wave id, 0..1023
  const int lane = threadIdx.x & 63;
  for (int i = 0; i < 64; ++i){
    const size_t word = (size_t)w * 64 + i;              // 0..65535
    const int v = mask[word * 64 + lane];
    const unsigned long long b = __ballot(v != 0);
    if (lane == 0) bits[word] = b;
  }
}

__global__ __launch_bounds__(256) void attn_fused(
    const float* __restrict__ Qg, const float* __restrict__ Kg, const float* __restrict__ Vg,
    const int* __restrict__ maskg, const unsigned long long* __restrict__ bitsg, int useBits,
    float* __restrict__ outg, float* __restrict__ probsg)
{
  __shared__ __align__(16) short Kl[64 * 64];
  __shared__ __align__(16) short Vt[64 * 64];
  __shared__ __align__(16) short Pl[4 * 16 * 64];

  const int tid  = threadIdx.x;
  const int wid  = tid >> 6;
  const int lane = tid & 63;
  const int lh   = lane >> 4;   // 0..3
  const int ll   = lane & 15;   // 0..15

  const int qt    = blockIdx.x & 31;   // q-tile fast: concurrent blocks share one bh's K/V in L2
  const int bh    = blockIdx.x >> 5;
  const int qbase = qt * QBLK;

  const float* Qb = Qg + (size_t)bh * S_LEN * DKC;
  const float* Kb = Kg + (size_t)bh * S_LEN * DKC;
  const float* Vb = Vg + (size_t)bh * S_LEN * DKC;
  float* outb   = outg   + (size_t)bh * S_LEN * DKC;
  float* probsb = probsg + (size_t)bh * S_LEN * S_LEN;

  // ---- Q fragments in registers (A-operand: row = lane&15, k = 8*(lane>>4)+j) ----
  const int qrow = qbase + wid * 16 + ll;
  short8v qf[2];
  #pragma unroll
  for (int h = 0; h < 2; ++h){
    const float4 a = *(const float4*)(Qb + (size_t)qrow * DKC + h * 32 + lh * 8);
    const float4 b = *(const float4*)(Qb + (size_t)qrow * DKC + h * 32 + lh * 8 + 4);
    short8v t;
    t[0]=f2bf(a.x); t[1]=f2bf(a.y); t[2]=f2bf(a.z); t[3]=f2bf(a.w);
    t[4]=f2bf(b.x); t[5]=f2bf(b.y); t[6]=f2bf(b.z); t[7]=f2bf(b.w);
    qf[h] = t;
  }

  const int q0 = qbase + wid * 16 + lh * 4;   // C-frag rows: q0 + j

  float m[4], l[4];
  #pragma unroll
  for (int j = 0; j < 4; ++j){ m[j] = -3.0e38f; l[j] = 0.f; }

  // ================= PASS A: row max + denom (online) =================
  for (int t = 0; t < S_LEN / 64; ++t){
    __syncthreads();
    stage_rows_bf16(Kl, Kb + (size_t)t * 64 * DKC, tid);
    __syncthreads();

    unsigned long long wbits[4];
    if (useBits){
      #pragma unroll
      for (int j = 0; j < 4; ++j) wbits[j] = bitsg[(size_t)(q0 + j) * 32 + t];
    }

    #pragma unroll
    for (int kt = 0; kt < 4; ++kt){
      const short8v kf0 = *(const short8v*)&Kl[swz(kt * 16 + ll, lh * 8)];
      const short8v kf1 = *(const short8v*)&Kl[swz(kt * 16 + ll, 32 + lh * 8)];
      f32x4 acc = (f32x4){0.f, 0.f, 0.f, 0.f};
      acc = __builtin_amdgcn_mfma_f32_16x16x32_bf16(qf[0], kf0, acc, 0, 0, 0);
      acc = __builtin_amdgcn_mfma_f32_16x16x32_bf16(qf[1], kf1, acc, 0, 0, 0);
      const int kcol = t * 64 + kt * 16 + ll;

      float s[4];
      #pragma unroll
      for (int j = 0; j < 4; ++j){
        int mv;
        if (useBits) mv = (int)((wbits[j] >> (kt * 16 + ll)) & 1ull);
        else         mv = (maskg[(size_t)(q0 + j) * S_LEN + kcol] != 0);
        s[j] = mv ? acc[j] * 0.125f : NEGV;
      }
      #pragma unroll
      for (int j = 0; j < 4; ++j){
        float tm = s[j];
        tm = fmaxf(tm, __shfl_xor(tm, 1, 64));
        tm = fmaxf(tm, __shfl_xor(tm, 2, 64));
        tm = fmaxf(tm, __shfl_xor(tm, 4, 64));
        tm = fmaxf(tm, __shfl_xor(tm, 8, 64));
        const float mn = fmaxf(m[j], tm);
        float p = __expf(s[j] - mn);
        p += __shfl_xor(p, 1, 64);
        p += __shfl_xor(p, 2, 64);
        p += __shfl_xor(p, 4, 64);
        p += __shfl_xor(p, 8, 64);
        l[j] = l[j] * __expf(m[j] - mn) + p;
        m[j] = mn;
      }
    }
  }

  float rl[4];
  #pragma unroll
  for (int j = 0; j < 4; ++j) rl[j] = 1.0f / l[j];

  // ================= PASS B: probs write + O = P.V =================
  f32x4 o[4];
  #pragma unroll
  for (int dt = 0; dt < 4; ++dt) o[dt] = (f32x4){0.f, 0.f, 0.f, 0.f};

  for (int t = 0; t < S_LEN / 64; ++t){
    __syncthreads();
    stage_rows_bf16(Kl, Kb + (size_t)t * 64 * DKC, tid);
    stage_vT_bf16 (Vt, Vb + (size_t)t * 64 * DKC, tid);
    __syncthreads();

    unsigned long long wbits[4];
    if (useBits){
      #pragma unroll
      for (int j = 0; j < 4; ++j) wbits[j] = bitsg[(size_t)(q0 + j) * 32 + t];
    }

    #pragma unroll
    for (int kt = 0; kt < 4; ++kt){
      const short8v kf0 = *(const short8v*)&Kl[swz(kt * 16 + ll, lh * 8)];
      const short8v kf1 = *(const short8v*)&Kl[swz(kt * 16 + ll, 32 + lh * 8)];
      f32x4 acc = (f32x4){0.f, 0.f, 0.f, 0.f};
      acc = __builtin_amdgcn_mfma_f32_16x16x32_bf16(qf[0], kf0, acc, 0, 0, 0);
      acc = __builtin_amdgcn_mfma_f32_16x16x32_bf16(qf[1], kf1, acc, 0, 0, 0);
      const int kcol = t * 64 + kt * 16 + ll;

      #pragma unroll
      for (int j = 0; j < 4; ++j){
        int mv;
        if (useBits) mv = (int)((wbits[j] >> (kt * 16 + ll)) & 1ull);
        else         mv = (maskg[(size_t)(q0 + j) * S_LEN + kcol] != 0);
        const float s = mv ? acc[j] * 0.125f : NEGV;
        const float p = __expf(s - m[j]) * rl[j];
        __builtin_nontemporal_store(p, &probsb[(size_t)(q0 + j) * S_LEN + kcol]);
        Pl[wid * 1024 + swz(lh * 4 + j, kt * 16 + ll)] = f2bf(p);
      }
    }
    // wave-private P tile: own writes must land before own reads
    asm volatile("s_waitcnt lgkmcnt(0)" ::: "memory");

    #pragma unroll
    for (int k32 = 0; k32 < 2; ++k32){
      const short8v pf = *(const short8v*)&Pl[wid * 1024 + swz(ll, k32 * 32 + lh * 8)];
      #pragma unroll
      for (int dt = 0; dt < 4; ++dt){
        const short8v vf = *(const short8v*)&Vt[swz(dt * 16 + ll, k32 * 32 + lh * 8)];
        o[dt] = __builtin_amdgcn_mfma_f32_16x16x32_bf16(pf, vf, o[dt], 0, 0, 0);
      }
    }
  }

  #pragma unroll
  for (int dt = 0; dt < 4; ++dt)
    #pragma unroll
    for (int j = 0; j < 4; ++j)
      __builtin_nontemporal_store(o[dt][j], &outb[(size_t)(q0 + j) * DKC + dt * 16 + ll]);
}

extern "C" void kernel_launch(void* const* d_in, const int* in_sizes, int n_in,
                              void* d_out, int out_size, void* d_ws, size_t ws_size,
                              hipStream_t stream) {
  const float* Q    = (const float*)d_in[0];
  const float* K    = (const float*)d_in[1];
  const float* V    = (const float*)d_in[2];
  const int*   mask = (const int*)d_in[3];

  float* out   = (float*)d_out;                         // [4,16,2048,64]  = 8388608 floats
  float* probs = out + (size_t)4 * 16 * 2048 * 64;      // [4,16,2048,2048]

  const size_t bits_bytes = (size_t)S_LEN * S_LEN / 8;  // 512 KiB
  const int useBits = (ws_size >= bits_bytes) ? 1 : 0;
  unsigned long long* bits = (unsigned long long*)d_ws;

  if (useBits) maskpack_kernel<<<256, 256, 0, stream>>>(mask, bits);
  attn_fused<<<64 * 32, 256, 0, stream>>>(Q, K, V, mask, bits, useBits, out, probs);
}

// Round 3
// 550.303 us; speedup vs baseline: 1.5935x; 1.5935x over previous
//
#include <hip/hip_runtime.h>
#include <hip/hip_bf16.h>

#define S_LEN 2048
#define NT    32
#define DKC   64
#define NEGV  (-1e9f)

typedef __attribute__((ext_vector_type(8))) short short8v;
typedef __attribute__((ext_vector_type(4))) float f32x4;

__device__ __forceinline__ short f2bf(float f){
  unsigned u = __builtin_bit_cast(unsigned, f);
  u += 0x7fffu + ((u >> 16) & 1u);          // RNE to bf16
  return (short)(u >> 16);
}

// swizzled element index for a [rows][64] bf16 tile (128B rows): XOR bits 3-5
__device__ __forceinline__ int swz(int row, int col){
  return (row * 64 + col) ^ ((row & 7) << 3);
}

// ---------------- fallback staging (no-ws path) ----------------
__device__ __forceinline__ void stage_rows_bf16(short* dst, const float* src, int tid){
  const int r  = tid >> 2;
  const int c0 = (tid & 3) * 16;
  const float* p = src + (size_t)r * DKC + c0;
  float4 a0 = *(const float4*)(p);
  float4 a1 = *(const float4*)(p + 4);
  float4 a2 = *(const float4*)(p + 8);
  float4 a3 = *(const float4*)(p + 12);
  short8v s0, s1;
  s0[0]=f2bf(a0.x); s0[1]=f2bf(a0.y); s0[2]=f2bf(a0.z); s0[3]=f2bf(a0.w);
  s0[4]=f2bf(a1.x); s0[5]=f2bf(a1.y); s0[6]=f2bf(a1.z); s0[7]=f2bf(a1.w);
  s1[0]=f2bf(a2.x); s1[1]=f2bf(a2.y); s1[2]=f2bf(a2.z); s1[3]=f2bf(a2.w);
  s1[4]=f2bf(a3.x); s1[5]=f2bf(a3.y); s1[6]=f2bf(a3.z); s1[7]=f2bf(a3.w);
  *(short8v*)&dst[swz(r, c0)]     = s0;
  *(short8v*)&dst[swz(r, c0 + 8)] = s1;
}

__device__ __forceinline__ void stage_vT_bf16(short* dst, const float* src, int tid){
  const int k  = tid >> 4;
  const int d0 = (tid & 15) * 4;
  #pragma unroll
  for (int i = 0; i < 4; ++i){
    const int kk = k + 16 * i;
    const float4 v = *(const float4*)(src + (size_t)kk * DKC + d0);
    dst[swz(d0 + 0, kk)] = f2bf(v.x);
    dst[swz(d0 + 1, kk)] = f2bf(v.y);
    dst[swz(d0 + 2, kk)] = f2bf(v.z);
    dst[swz(d0 + 3, kk)] = f2bf(v.w);
  }
}

// ---------------- precompute kernels ----------------
__global__ void maskpack_kernel(const int* __restrict__ mask, unsigned long long* __restrict__ bits){
  const int w    = blockIdx.x * 4 + (threadIdx.x >> 6);
  const int lane = threadIdx.x & 63;
  for (int i = 0; i < 64; ++i){
    const size_t word = (size_t)w * 64 + i;
    const int v = mask[word * 64 + lane];
    const unsigned long long b = __ballot(v != 0);
    if (lane == 0) bits[word] = b;
  }
}

// Convert one 64x64 tile of K -> bf16 swizzled image [r][d], and V -> transposed image [d][k].
__global__ __launch_bounds__(256) void kv_convert(const float* __restrict__ Kg, const float* __restrict__ Vg,
                                                  short* __restrict__ Kimg, short* __restrict__ Vimg){
  __shared__ float Vf[64][65];
  const int tid = threadIdx.x;
  const size_t tile = blockIdx.x;               // bh*32 + t
  const float* Kb = Kg + tile * (64 * 64);
  const float* Vb = Vg + tile * (64 * 64);
  short* Ki = Kimg + tile * 4096;
  short* Vi = Vimg + tile * 4096;
  // K: direct
  {
    const int r = tid >> 2, c0 = (tid & 3) * 16;
    const float* p = Kb + (size_t)r * 64 + c0;
    float4 a0 = *(const float4*)(p);
    float4 a1 = *(const float4*)(p + 4);
    float4 a2 = *(const float4*)(p + 8);
    float4 a3 = *(const float4*)(p + 12);
    short8v s0, s1;
    s0[0]=f2bf(a0.x); s0[1]=f2bf(a0.y); s0[2]=f2bf(a0.z); s0[3]=f2bf(a0.w);
    s0[4]=f2bf(a1.x); s0[5]=f2bf(a1.y); s0[6]=f2bf(a1.z); s0[7]=f2bf(a1.w);
    s1[0]=f2bf(a2.x); s1[1]=f2bf(a2.y); s1[2]=f2bf(a2.z); s1[3]=f2bf(a2.w);
    s1[4]=f2bf(a3.x); s1[5]=f2bf(a3.y); s1[6]=f2bf(a3.z); s1[7]=f2bf(a3.w);
    *(short8v*)&Ki[swz(r, c0)]     = s0;
    *(short8v*)&Ki[swz(r, c0 + 8)] = s1;
  }
  // V: LDS transpose
  {
    const int k = tid >> 2, c0 = (tid & 3) * 16;
    const float* p = Vb + (size_t)k * 64 + c0;
    float4 a0 = *(const float4*)(p);
    float4 a1 = *(const float4*)(p + 4);
    float4 a2 = *(const float4*)(p + 8);
    float4 a3 = *(const float4*)(p + 12);
    Vf[k][c0+0]=a0.x; Vf[k][c0+1]=a0.y; Vf[k][c0+2]=a0.z; Vf[k][c0+3]=a0.w;
    Vf[k][c0+4]=a1.x; Vf[k][c0+5]=a1.y; Vf[k][c0+6]=a1.z; Vf[k][c0+7]=a1.w;
    Vf[k][c0+8]=a2.x; Vf[k][c0+9]=a2.y; Vf[k][c0+10]=a2.z; Vf[k][c0+11]=a2.w;
    Vf[k][c0+12]=a3.x; Vf[k][c0+13]=a3.y; Vf[k][c0+14]=a3.z; Vf[k][c0+15]=a3.w;
  }
  __syncthreads();
  {
    const int d = tid >> 2, k0 = (tid & 3) * 16;
    short8v s0, s1;
    #pragma unroll
    for (int i = 0; i < 8; ++i) s0[i] = f2bf(Vf[k0 + i][d]);
    #pragma unroll
    for (int i = 0; i < 8; ++i) s1[i] = f2bf(Vf[k0 + 8 + i][d]);
    *(short8v*)&Vi[swz(d, k0)]     = s0;
    *(short8v*)&Vi[swz(d, k0 + 8)] = s1;
  }
}

// ---------------- main fused kernel (swapped QK^T: lane owns one q-row) ----------------
template<int WS, int BITS>
__global__ __launch_bounds__(256) void attn2(
    const float* __restrict__ Qg, const float* __restrict__ Kg, const float* __restrict__ Vg,
    const int* __restrict__ maskg, const unsigned long long* __restrict__ bitsg,
    const short* __restrict__ Kimg, const short* __restrict__ Vimg,
    float* __restrict__ outg, float* __restrict__ probsg)
{
  __shared__ __align__(16) short Kl[WS ? 16 : 4096];
  __shared__ __align__(16) short Vt[WS ? 16 : 4096];
  __shared__ __align__(16) short Pl[4096];          // 2KB per wave, wave-private

  const int tid  = threadIdx.x;
  const int wid  = tid >> 6;
  const int lane = tid & 63;
  const int lh   = lane >> 4;
  const int ll   = lane & 15;

  const int qt    = blockIdx.x & 31;
  const int bh    = blockIdx.x >> 5;
  const int qbase = qt * 64;
  const int qrow  = qbase + wid * 16 + ll;   // this lane's q-row (softmax/probs/bits)

  const float* Qb = Qg + (size_t)bh * S_LEN * DKC;
  const float* Kb = Kg + (size_t)bh * S_LEN * DKC;
  const float* Vb = Vg + (size_t)bh * S_LEN * DKC;
  float* outb   = outg   + (size_t)bh * S_LEN * DKC;
  float* probsb = probsg + (size_t)bh * S_LEN * S_LEN;
  const short* Kib = Kimg + (size_t)bh * NT * 4096;
  const short* Vib = Vimg + (size_t)bh * NT * 4096;

  // Q fragments (B-operand: col = lane&15 = q, k = 8*lh + e)
  short8v qf[2];
  #pragma unroll
  for (int h = 0; h < 2; ++h){
    const float4 a = *(const float4*)(Qb + (size_t)qrow * DKC + h * 32 + lh * 8);
    const float4 b = *(const float4*)(Qb + (size_t)qrow * DKC + h * 32 + lh * 8 + 4);
    short8v t;
    t[0]=f2bf(a.x); t[1]=f2bf(a.y); t[2]=f2bf(a.z); t[3]=f2bf(a.w);
    t[4]=f2bf(b.x); t[5]=f2bf(b.y); t[6]=f2bf(b.z); t[7]=f2bf(b.w);
    qf[h] = t;
  }

  float m = -3.0e38f, l = 0.f;

  // ================= PASS A: row max + denom =================
  for (int t = 0; t < NT; ++t){
    f32x4 acc[4];
    if constexpr (WS){
      const short* Kt = Kib + t * 4096;
      #pragma unroll
      for (int kt = 0; kt < 4; ++kt){
        const short8v kf0 = *(const short8v*)(Kt + swz(kt * 16 + ll, lh * 8));
        const short8v kf1 = *(const short8v*)(Kt + swz(kt * 16 + ll, 32 + lh * 8));
        f32x4 a = (f32x4){0.f, 0.f, 0.f, 0.f};
        a = __builtin_amdgcn_mfma_f32_16x16x32_bf16(kf0, qf[0], a, 0, 0, 0);
        a = __builtin_amdgcn_mfma_f32_16x16x32_bf16(kf1, qf[1], a, 0, 0, 0);
        acc[kt] = a;
      }
    } else {
      __syncthreads();
      stage_rows_bf16(Kl, Kb + (size_t)t * 64 * DKC, tid);
      __syncthreads();
      #pragma unroll
      for (int kt = 0; kt < 4; ++kt){
        const short8v kf0 = *(const short8v*)&Kl[swz(kt * 16 + ll, lh * 8)];
        const short8v kf1 = *(const short8v*)&Kl[swz(kt * 16 + ll, 32 + lh * 8)];
        f32x4 a = (f32x4){0.f, 0.f, 0.f, 0.f};
        a = __builtin_amdgcn_mfma_f32_16x16x32_bf16(kf0, qf[0], a, 0, 0, 0);
        a = __builtin_amdgcn_mfma_f32_16x16x32_bf16(kf1, qf[1], a, 0, 0, 0);
        acc[kt] = a;
      }
    }
    unsigned long long wb = 0;
    if constexpr (BITS) wb = bitsg[(size_t)qrow * NT + t];
    float s[16];
    float tm = -3.0e38f;
    #pragma unroll
    for (int kt = 0; kt < 4; ++kt)
      #pragma unroll
      for (int j = 0; j < 4; ++j){
        const int bi = kt * 16 + lh * 4 + j;
        int keep;
        if constexpr (BITS) keep = (int)((wb >> bi) & 1ull);
        else                keep = maskg[(size_t)qrow * S_LEN + t * 64 + bi] != 0;
        const float v = keep ? acc[kt][j] * 0.125f : NEGV;
        s[kt * 4 + j] = v;
        tm = fmaxf(tm, v);
      }
    tm = fmaxf(tm, __shfl_xor(tm, 16, 64));
    tm = fmaxf(tm, __shfl_xor(tm, 32, 64));
    const float mn = fmaxf(m, tm);
    float ss = 0.f;
    #pragma unroll
    for (int i = 0; i < 16; ++i) ss += __expf(s[i] - mn);
    ss += __shfl_xor(ss, 16, 64);
    ss += __shfl_xor(ss, 32, 64);
    l = l * __expf(m - mn) + ss;
    m = mn;
  }
  const float rl = 1.0f / l;

  // ================= PASS B: probs + O = P.V =================
  f32x4 o[4];
  #pragma unroll
  for (int dt = 0; dt < 4; ++dt) o[dt] = (f32x4){0.f, 0.f, 0.f, 0.f};

  for (int t = 0; t < NT; ++t){
    f32x4 acc[4];
    if constexpr (WS){
      const short* Kt = Kib + t * 4096;
      #pragma unroll
      for (int kt = 0; kt < 4; ++kt){
        const short8v kf0 = *(const short8v*)(Kt + swz(kt * 16 + ll, lh * 8));
        const short8v kf1 = *(const short8v*)(Kt + swz(kt * 16 + ll, 32 + lh * 8));
        f32x4 a = (f32x4){0.f, 0.f, 0.f, 0.f};
        a = __builtin_amdgcn_mfma_f32_16x16x32_bf16(kf0, qf[0], a, 0, 0, 0);
        a = __builtin_amdgcn_mfma_f32_16x16x32_bf16(kf1, qf[1], a, 0, 0, 0);
        acc[kt] = a;
      }
    } else {
      __syncthreads();
      stage_rows_bf16(Kl, Kb + (size_t)t * 64 * DKC, tid);
      stage_vT_bf16 (Vt, Vb + (size_t)t * 64 * DKC, tid);
      __syncthreads();
      #pragma unroll
      for (int kt = 0; kt < 4; ++kt){
        const short8v kf0 = *(const short8v*)&Kl[swz(kt * 16 + ll, lh * 8)];
        const short8v kf1 = *(const short8v*)&Kl[swz(kt * 16 + ll, 32 + lh * 8)];
        f32x4 a = (f32x4){0.f, 0.f, 0.f, 0.f};
        a = __builtin_amdgcn_mfma_f32_16x16x32_bf16(kf0, qf[0], a, 0, 0, 0);
        a = __builtin_amdgcn_mfma_f32_16x16x32_bf16(kf1, qf[1], a, 0, 0, 0);
        acc[kt] = a;
      }
    }
    unsigned long long wb = 0;
    if constexpr (BITS) wb = bitsg[(size_t)qrow * NT + t];
    float p[16];
    #pragma unroll
    for (int kt = 0; kt < 4; ++kt)
      #pragma unroll
      for (int j = 0; j < 4; ++j){
        const int bi = kt * 16 + lh * 4 + j;
        int keep;
        if constexpr (BITS) keep = (int)((wb >> bi) & 1ull);
        else                keep = maskg[(size_t)qrow * S_LEN + t * 64 + bi] != 0;
        const float sv = keep ? acc[kt][j] * 0.125f : NEGV;
        p[kt * 4 + j] = __expf(sv - m) * rl;
      }
    #pragma unroll
    for (int kt = 0; kt < 4; ++kt){
      f32x4 pv;
      pv[0] = p[kt*4+0]; pv[1] = p[kt*4+1]; pv[2] = p[kt*4+2]; pv[3] = p[kt*4+3];
      __builtin_nontemporal_store(pv, (f32x4*)&probsb[(size_t)qrow * S_LEN + t * 64 + kt * 16 + lh * 4]);
      short4 ps;
      ps.x = f2bf(p[kt*4+0]); ps.y = f2bf(p[kt*4+1]);
      ps.z = f2bf(p[kt*4+2]); ps.w = f2bf(p[kt*4+3]);
      *(short4*)&Pl[wid * 1024 + swz(ll, kt * 16 + lh * 4)] = ps;
    }
    asm volatile("s_waitcnt lgkmcnt(0)" ::: "memory");
    __builtin_amdgcn_sched_barrier(0);
    #pragma unroll
    for (int k32 = 0; k32 < 2; ++k32){
      const short8v pf = *(const short8v*)&Pl[wid * 1024 + swz(ll, k32 * 32 + lh * 8)];
      #pragma unroll
      for (int dt = 0; dt < 4; ++dt){
        short8v vf;
        if constexpr (WS) vf = *(const short8v*)(Vib + t * 4096 + swz(dt * 16 + ll, k32 * 32 + lh * 8));
        else              vf = *(const short8v*)&Vt[swz(dt * 16 + ll, k32 * 32 + lh * 8)];
        o[dt] = __builtin_amdgcn_mfma_f32_16x16x32_bf16(pf, vf, o[dt], 0, 0, 0);
      }
    }
  }

  #pragma unroll
  for (int dt = 0; dt < 4; ++dt)
    #pragma unroll
    for (int j = 0; j < 4; ++j)
      __builtin_nontemporal_store(o[dt][j], &outb[(size_t)(qbase + wid * 16 + lh * 4 + j) * DKC + dt * 16 + ll]);
}

extern "C" void kernel_launch(void* const* d_in, const int* in_sizes, int n_in,
                              void* d_out, int out_size, void* d_ws, size_t ws_size,
                              hipStream_t stream) {
  const float* Q    = (const float*)d_in[0];
  const float* K    = (const float*)d_in[1];
  const float* V    = (const float*)d_in[2];
  const int*   mask = (const int*)d_in[3];

  float* out   = (float*)d_out;
  float* probs = out + (size_t)4 * 16 * 2048 * 64;

  const size_t bitsB = (size_t)S_LEN * S_LEN / 8;          // 512 KiB
  const size_t imgB  = (size_t)64 * NT * 4096 * 2;         // 16 MiB each
  unsigned long long* bits = (unsigned long long*)d_ws;
  short* Kimg = (short*)((char*)d_ws + bitsB);
  short* Vimg = (short*)((char*)d_ws + bitsB + imgB);

  int mode;
  if      (ws_size >= bitsB + 2 * imgB) mode = 2;
  else if (ws_size >= bitsB)            mode = 1;
  else                                  mode = 0;

  if (mode >= 1) maskpack_kernel<<<256, 256, 0, stream>>>(mask, bits);
  if (mode == 2) kv_convert<<<64 * NT, 256, 0, stream>>>(K, V, Kimg, Vimg);

  if (mode == 2)
    attn2<1,1><<<64 * 32, 256, 0, stream>>>(Q, K, V, mask, bits, Kimg, Vimg, out, probs);
  else if (mode == 1)
    attn2<0,1><<<64 * 32, 256, 0, stream>>>(Q, K, V, mask, bits, Kimg, Vimg, out, probs);
  else
    attn2<0,0><<<64 * 32, 256, 0, stream>>>(Q, K, V, mask, bits, Kimg, Vimg, out, probs);
}

// Round 4
// 517.071 us; speedup vs baseline: 1.6959x; 1.0643x over previous
//
#include <hip/hip_runtime.h>
#include <hip/hip_bf16.h>

#define S_LEN 2048
#define NT    32
#define DKC   64
#define NEGV  (-1e9f)
// 0.125 * log2(e): folds the 1/sqrt(64) scale and the exp->exp2 conversion
#define C_SC  0.18033688011112042f

typedef __attribute__((ext_vector_type(8))) short short8v;
typedef __attribute__((ext_vector_type(4))) float f32x4;

__device__ __forceinline__ short f2bf(float f){
  unsigned u = __builtin_bit_cast(unsigned, f);
  u += 0x7fffu + ((u >> 16) & 1u);          // RNE to bf16
  return (short)(u >> 16);
}

// swizzled element index for a [rows][64] bf16 tile (128B rows): XOR bits 3-5
__device__ __forceinline__ int swz(int row, int col){
  return (row * 64 + col) ^ ((row & 7) << 3);
}

// ---------------- fallback staging (no-ws path) ----------------
__device__ __forceinline__ void stage_rows_bf16(short* dst, const float* src, int tid){
  const int r  = tid >> 2;
  const int c0 = (tid & 3) * 16;
  const float* p = src + (size_t)r * DKC + c0;
  float4 a0 = *(const float4*)(p);
  float4 a1 = *(const float4*)(p + 4);
  float4 a2 = *(const float4*)(p + 8);
  float4 a3 = *(const float4*)(p + 12);
  short8v s0, s1;
  s0[0]=f2bf(a0.x); s0[1]=f2bf(a0.y); s0[2]=f2bf(a0.z); s0[3]=f2bf(a0.w);
  s0[4]=f2bf(a1.x); s0[5]=f2bf(a1.y); s0[6]=f2bf(a1.z); s0[7]=f2bf(a1.w);
  s1[0]=f2bf(a2.x); s1[1]=f2bf(a2.y); s1[2]=f2bf(a2.z); s1[3]=f2bf(a2.w);
  s1[4]=f2bf(a3.x); s1[5]=f2bf(a3.y); s1[6]=f2bf(a3.z); s1[7]=f2bf(a3.w);
  *(short8v*)&dst[swz(r, c0)]     = s0;
  *(short8v*)&dst[swz(r, c0 + 8)] = s1;
}

__device__ __forceinline__ void stage_vT_bf16(short* dst, const float* src, int tid){
  const int k  = tid >> 4;
  const int d0 = (tid & 15) * 4;
  #pragma unroll
  for (int i = 0; i < 4; ++i){
    const int kk = k + 16 * i;
    const float4 v = *(const float4*)(src + (size_t)kk * DKC + d0);
    dst[swz(d0 + 0, kk)] = f2bf(v.x);
    dst[swz(d0 + 1, kk)] = f2bf(v.y);
    dst[swz(d0 + 2, kk)] = f2bf(v.z);
    dst[swz(d0 + 3, kk)] = f2bf(v.w);
  }
}

// ---------------- precompute kernels ----------------
__global__ void maskpack_kernel(const int* __restrict__ mask, unsigned long long* __restrict__ bits){
  const int w    = blockIdx.x * 4 + (threadIdx.x >> 6);
  const int lane = threadIdx.x & 63;
  for (int i = 0; i < 64; ++i){
    const size_t word = (size_t)w * 64 + i;
    const int v = mask[word * 64 + lane];
    const unsigned long long b = __ballot(v != 0);
    if (lane == 0) bits[word] = b;
  }
}

// Convert one 64x64 tile of K -> bf16 swizzled image [r][d], and V -> transposed image [d][k].
__global__ __launch_bounds__(256) void kv_convert(const float* __restrict__ Kg, const float* __restrict__ Vg,
                                                  short* __restrict__ Kimg, short* __restrict__ Vimg){
  __shared__ float Vf[64][65];
  const int tid = threadIdx.x;
  const size_t tile = blockIdx.x;               // bh*32 + t
  const float* Kb = Kg + tile * (64 * 64);
  const float* Vb = Vg + tile * (64 * 64);
  short* Ki = Kimg + tile * 4096;
  short* Vi = Vimg + tile * 4096;
  // K: direct
  {
    const int r = tid >> 2, c0 = (tid & 3) * 16;
    const float* p = Kb + (size_t)r * 64 + c0;
    float4 a0 = *(const float4*)(p);
    float4 a1 = *(const float4*)(p + 4);
    float4 a2 = *(const float4*)(p + 8);
    float4 a3 = *(const float4*)(p + 12);
    short8v s0, s1;
    s0[0]=f2bf(a0.x); s0[1]=f2bf(a0.y); s0[2]=f2bf(a0.z); s0[3]=f2bf(a0.w);
    s0[4]=f2bf(a1.x); s0[5]=f2bf(a1.y); s0[6]=f2bf(a1.z); s0[7]=f2bf(a1.w);
    s1[0]=f2bf(a2.x); s1[1]=f2bf(a2.y); s1[2]=f2bf(a2.z); s1[3]=f2bf(a2.w);
    s1[4]=f2bf(a3.x); s1[5]=f2bf(a3.y); s1[6]=f2bf(a3.z); s1[7]=f2bf(a3.w);
    *(short8v*)&Ki[swz(r, c0)]     = s0;
    *(short8v*)&Ki[swz(r, c0 + 8)] = s1;
  }
  // V: LDS transpose
  {
    const int k = tid >> 2, c0 = (tid & 3) * 16;
    const float* p = Vb + (size_t)k * 64 + c0;
    float4 a0 = *(const float4*)(p);
    float4 a1 = *(const float4*)(p + 4);
    float4 a2 = *(const float4*)(p + 8);
    float4 a3 = *(const float4*)(p + 12);
    Vf[k][c0+0]=a0.x; Vf[k][c0+1]=a0.y; Vf[k][c0+2]=a0.z; Vf[k][c0+3]=a0.w;
    Vf[k][c0+4]=a1.x; Vf[k][c0+5]=a1.y; Vf[k][c0+6]=a1.z; Vf[k][c0+7]=a1.w;
    Vf[k][c0+8]=a2.x; Vf[k][c0+9]=a2.y; Vf[k][c0+10]=a2.z; Vf[k][c0+11]=a2.w;
    Vf[k][c0+12]=a3.x; Vf[k][c0+13]=a3.y; Vf[k][c0+14]=a3.z; Vf[k][c0+15]=a3.w;
  }
  __syncthreads();
  {
    const int d = tid >> 2, k0 = (tid & 3) * 16;
    short8v s0, s1;
    #pragma unroll
    for (int i = 0; i < 8; ++i) s0[i] = f2bf(Vf[k0 + i][d]);
    #pragma unroll
    for (int i = 0; i < 8; ++i) s1[i] = f2bf(Vf[k0 + 8 + i][d]);
    *(short8v*)&Vi[swz(d, k0)]     = s0;
    *(short8v*)&Vi[swz(d, k0 + 8)] = s1;
  }
}

// ---------------- split-path helpers ----------------
__device__ __forceinline__ void loadK(short8v (&kf)[8], const short* Kt, int ll, int lh){
  #pragma unroll
  for (int kt = 0; kt < 4; ++kt){
    kf[kt*2+0] = *(const short8v*)(Kt + swz(kt * 16 + ll, lh * 8));
    kf[kt*2+1] = *(const short8v*)(Kt + swz(kt * 16 + ll, 32 + lh * 8));
  }
}

__device__ __forceinline__ float tile_sum(const short8v (&kf)[8], const short8v (&qf)[2],
                                          unsigned long long wb, int lh){
  float s = 0.f;
  #pragma unroll
  for (int kt = 0; kt < 4; ++kt){
    f32x4 a = (f32x4){0.f, 0.f, 0.f, 0.f};
    a = __builtin_amdgcn_mfma_f32_16x16x32_bf16(kf[kt*2+0], qf[0], a, 0, 0, 0);
    a = __builtin_amdgcn_mfma_f32_16x16x32_bf16(kf[kt*2+1], qf[1], a, 0, 0, 0);
    #pragma unroll
    for (int j = 0; j < 4; ++j){
      const int bi = kt * 16 + lh * 4 + j;
      const float arg = ((wb >> bi) & 1ull) ? a[j] * C_SC : NEGV;
      s += exp2f(arg);
    }
  }
  return s;
}

// ---------------- PASS 1: denominators (log2 of row sums) ----------------
__global__ __launch_bounds__(256) void pass_sum(
    const float* __restrict__ Qg, const unsigned long long* __restrict__ bitsg,
    const short* __restrict__ Kimg, float* __restrict__ lnl)
{
  const int tid  = threadIdx.x;
  const int wid  = tid >> 6;
  const int lane = tid & 63;
  const int lh   = lane >> 4;
  const int ll   = lane & 15;

  const int bh   = blockIdx.x & 63;     // bh-major: all q-tiles of a bh on one XCD
  const int qt   = blockIdx.x >> 6;
  const int qrow = qt * 64 + wid * 16 + ll;

  const float* Qb  = Qg + (size_t)bh * S_LEN * DKC;
  const short* Kib = Kimg + (size_t)bh * NT * 4096;

  short8v qf[2];
  #pragma unroll
  for (int h = 0; h < 2; ++h){
    const float4 a = *(const float4*)(Qb + (size_t)qrow * DKC + h * 32 + lh * 8);
    const float4 b = *(const float4*)(Qb + (size_t)qrow * DKC + h * 32 + lh * 8 + 4);
    short8v t;
    t[0]=f2bf(a.x); t[1]=f2bf(a.y); t[2]=f2bf(a.z); t[3]=f2bf(a.w);
    t[4]=f2bf(b.x); t[5]=f2bf(b.y); t[6]=f2bf(b.z); t[7]=f2bf(b.w);
    qf[h] = t;
  }

  float sum = 0.f;
  short8v ka[8], kb[8];
  loadK(ka, Kib, ll, lh);
  for (int tt = 0; tt < NT; tt += 2){
    loadK(kb, Kib + (size_t)(tt + 1) * 4096, ll, lh);
    sum += tile_sum(ka, qf, bitsg[(size_t)qrow * NT + tt], lh);
    const int nx = (tt + 2 < NT) ? tt + 2 : NT - 1;
    loadK(ka, Kib + (size_t)nx * 4096, ll, lh);
    sum += tile_sum(kb, qf, bitsg[(size_t)qrow * NT + tt + 1], lh);
  }
  sum += __shfl_xor(sum, 16, 64);
  sum += __shfl_xor(sum, 32, 64);
  if (lh == 0) lnl[bh * S_LEN + qrow] = __log2f(sum);
}

// ---------------- PASS 2: probs + O = P.V ----------------
__global__ __launch_bounds__(256) void pass_out(
    const float* __restrict__ Qg, const unsigned long long* __restrict__ bitsg,
    const short* __restrict__ Kimg, const short* __restrict__ Vimg,
    const float* __restrict__ lnl, float* __restrict__ outg, float* __restrict__ probsg)
{
  __shared__ __align__(16) short Pl[4096];   // 2KB per wave, wave-private

  const int tid  = threadIdx.x;
  const int wid  = tid >> 6;
  const int lane = tid & 63;
  const int lh   = lane >> 4;
  const int ll   = lane & 15;

  const int bh   = blockIdx.x & 63;
  const int qt   = blockIdx.x >> 6;
  const int qrow = qt * 64 + wid * 16 + ll;

  const float* Qb  = Qg + (size_t)bh * S_LEN * DKC;
  const short* Kib = Kimg + (size_t)bh * NT * 4096;
  const short* Vib = Vimg + (size_t)bh * NT * 4096;
  float* outb   = outg   + (size_t)bh * S_LEN * DKC;
  float* probsb = probsg + (size_t)bh * S_LEN * S_LEN;

  short8v qf[2];
  #pragma unroll
  for (int h = 0; h < 2; ++h){
    const float4 a = *(const float4*)(Qb + (size_t)qrow * DKC + h * 32 + lh * 8);
    const float4 b = *(const float4*)(Qb + (size_t)qrow * DKC + h * 32 + lh * 8 + 4);
    short8v t;
    t[0]=f2bf(a.x); t[1]=f2bf(a.y); t[2]=f2bf(a.z); t[3]=f2bf(a.w);
    t[4]=f2bf(b.x); t[5]=f2bf(b.y); t[6]=f2bf(b.z); t[7]=f2bf(b.w);
    qf[h] = t;
  }
  const float rlog = lnl[bh * S_LEN + qrow];

  f32x4 o[4];
  #pragma unroll
  for (int dt = 0; dt < 4; ++dt) o[dt] = (f32x4){0.f, 0.f, 0.f, 0.f};

  short8v ka[8], kb[8];
  loadK(ka, Kib, ll, lh);

  #define TILE_OUT(KF, T)                                                               \
  {                                                                                     \
    const int t_ = (T);                                                                 \
    const unsigned long long wb = bitsg[(size_t)qrow * NT + t_];                        \
    f32x4 acc[4];                                                                       \
    _Pragma("unroll")                                                                   \
    for (int kt = 0; kt < 4; ++kt){                                                     \
      f32x4 a = (f32x4){0.f, 0.f, 0.f, 0.f};                                            \
      a = __builtin_amdgcn_mfma_f32_16x16x32_bf16(KF[kt*2+0], qf[0], a, 0, 0, 0);       \
      a = __builtin_amdgcn_mfma_f32_16x16x32_bf16(KF[kt*2+1], qf[1], a, 0, 0, 0);       \
      acc[kt] = a;                                                                      \
    }                                                                                   \
    short8v vf[8];                                                                      \
    _Pragma("unroll")                                                                   \
    for (int k32 = 0; k32 < 2; ++k32)                                                   \
      _Pragma("unroll")                                                                 \
      for (int dt = 0; dt < 4; ++dt)                                                    \
        vf[k32*4+dt] = *(const short8v*)(Vib + (size_t)t_ * 4096 +                      \
                                         swz(dt * 16 + ll, k32 * 32 + lh * 8));         \
    _Pragma("unroll")                                                                   \
    for (int kt = 0; kt < 4; ++kt){                                                     \
      float p[4];                                                                       \
      _Pragma("unroll")                                                                 \
      for (int j = 0; j < 4; ++j){                                                      \
        const int bi = kt * 16 + lh * 4 + j;                                            \
        const float arg = ((wb >> bi) & 1ull) ? fmaf(acc[kt][j], C_SC, -rlog) : NEGV;   \
        p[j] = exp2f(arg);                                                              \
      }                                                                                 \
      f32x4 pv; pv[0]=p[0]; pv[1]=p[1]; pv[2]=p[2]; pv[3]=p[3];                         \
      __builtin_nontemporal_store(pv,                                                   \
        (f32x4*)&probsb[(size_t)qrow * S_LEN + t_ * 64 + kt * 16 + lh * 4]);            \
      short4 ps; ps.x=f2bf(p[0]); ps.y=f2bf(p[1]); ps.z=f2bf(p[2]); ps.w=f2bf(p[3]);    \
      *(short4*)&Pl[wid * 1024 + swz(ll, kt * 16 + lh * 4)] = ps;                       \
    }                                                                                   \
    asm volatile("s_waitcnt lgkmcnt(0)" ::: "memory");                                  \
    __builtin_amdgcn_sched_barrier(0);                                                  \
    _Pragma("unroll")                                                                   \
    for (int k32 = 0; k32 < 2; ++k32){                                                  \
      const short8v pf = *(const short8v*)&Pl[wid * 1024 + swz(ll, k32 * 32 + lh * 8)]; \
      _Pragma("unroll")                                                                 \
      for (int dt = 0; dt < 4; ++dt)                                                    \
        o[dt] = __builtin_amdgcn_mfma_f32_16x16x32_bf16(pf, vf[k32*4+dt], o[dt], 0,0,0);\
    }                                                                                   \
  }

  for (int tt = 0; tt < NT; tt += 2){
    loadK(kb, Kib + (size_t)(tt + 1) * 4096, ll, lh);
    TILE_OUT(ka, tt);
    const int nx = (tt + 2 < NT) ? tt + 2 : NT - 1;
    loadK(ka, Kib + (size_t)nx * 4096, ll, lh);
    TILE_OUT(kb, tt + 1);
  }
  #undef TILE_OUT

  #pragma unroll
  for (int dt = 0; dt < 4; ++dt)
    #pragma unroll
    for (int j = 0; j < 4; ++j)
      __builtin_nontemporal_store(o[dt][j], &outb[(size_t)(qt * 64 + wid * 16 + lh * 4 + j) * DKC + dt * 16 + ll]);
}

// ---------------- fallback: monolithic two-pass with LDS staging (round-3, WS=0) ----------------
template<int BITS>
__global__ __launch_bounds__(256) void attn_fb(
    const float* __restrict__ Qg, const float* __restrict__ Kg, const float* __restrict__ Vg,
    const int* __restrict__ maskg, const unsigned long long* __restrict__ bitsg,
    float* __restrict__ outg, float* __restrict__ probsg)
{
  __shared__ __align__(16) short Kl[4096];
  __shared__ __align__(16) short Vt[4096];
  __shared__ __align__(16) short Pl[4096];

  const int tid  = threadIdx.x;
  const int wid  = tid >> 6;
  const int lane = tid & 63;
  const int lh   = lane >> 4;
  const int ll   = lane & 15;

  const int qt    = blockIdx.x & 31;
  const int bh    = blockIdx.x >> 5;
  const int qbase = qt * 64;
  const int qrow  = qbase + wid * 16 + ll;

  const float* Qb = Qg + (size_t)bh * S_LEN * DKC;
  const float* Kb = Kg + (size_t)bh * S_LEN * DKC;
  const float* Vb = Vg + (size_t)bh * S_LEN * DKC;
  float* outb   = outg   + (size_t)bh * S_LEN * DKC;
  float* probsb = probsg + (size_t)bh * S_LEN * S_LEN;

  short8v qf[2];
  #pragma unroll
  for (int h = 0; h < 2; ++h){
    const float4 a = *(const float4*)(Qb + (size_t)qrow * DKC + h * 32 + lh * 8);
    const float4 b = *(const float4*)(Qb + (size_t)qrow * DKC + h * 32 + lh * 8 + 4);
    short8v t;
    t[0]=f2bf(a.x); t[1]=f2bf(a.y); t[2]=f2bf(a.z); t[3]=f2bf(a.w);
    t[4]=f2bf(b.x); t[5]=f2bf(b.y); t[6]=f2bf(b.z); t[7]=f2bf(b.w);
    qf[h] = t;
  }

  float sum = 0.f;
  for (int t = 0; t < NT; ++t){
    __syncthreads();
    stage_rows_bf16(Kl, Kb + (size_t)t * 64 * DKC, tid);
    __syncthreads();
    unsigned long long wb = 0;
    if constexpr (BITS) wb = bitsg[(size_t)qrow * NT + t];
    #pragma unroll
    for (int kt = 0; kt < 4; ++kt){
      const short8v kf0 = *(const short8v*)&Kl[swz(kt * 16 + ll, lh * 8)];
      const short8v kf1 = *(const short8v*)&Kl[swz(kt * 16 + ll, 32 + lh * 8)];
      f32x4 a = (f32x4){0.f, 0.f, 0.f, 0.f};
      a = __builtin_amdgcn_mfma_f32_16x16x32_bf16(kf0, qf[0], a, 0, 0, 0);
      a = __builtin_amdgcn_mfma_f32_16x16x32_bf16(kf1, qf[1], a, 0, 0, 0);
      #pragma unroll
      for (int j = 0; j < 4; ++j){
        const int bi = kt * 16 + lh * 4 + j;
        int keep;
        if constexpr (BITS) keep = (int)((wb >> bi) & 1ull);
        else                keep = maskg[(size_t)qrow * S_LEN + t * 64 + bi] != 0;
        sum += exp2f(keep ? a[j] * C_SC : NEGV);
      }
    }
  }
  sum += __shfl_xor(sum, 16, 64);
  sum += __shfl_xor(sum, 32, 64);
  const float rlog = __log2f(sum);

  f32x4 o[4];
  #pragma unroll
  for (int dt = 0; dt < 4; ++dt) o[dt] = (f32x4){0.f, 0.f, 0.f, 0.f};

  for (int t = 0; t < NT; ++t){
    __syncthreads();
    stage_rows_bf16(Kl, Kb + (size_t)t * 64 * DKC, tid);
    stage_vT_bf16 (Vt, Vb + (size_t)t * 64 * DKC, tid);
    __syncthreads();
    f32x4 acc[4];
    #pragma unroll
    for (int kt = 0; kt < 4; ++kt){
      const short8v kf0 = *(const short8v*)&Kl[swz(kt * 16 + ll, lh * 8)];
      const short8v kf1 = *(const short8v*)&Kl[swz(kt * 16 + ll, 32 + lh * 8)];
      f32x4 a = (f32x4){0.f, 0.f, 0.f, 0.f};
      a = __builtin_amdgcn_mfma_f32_16x16x32_bf16(kf0, qf[0], a, 0, 0, 0);
      a = __builtin_amdgcn_mfma_f32_16x16x32_bf16(kf1, qf[1], a, 0, 0, 0);
      acc[kt] = a;
    }
    unsigned long long wb = 0;
    if constexpr (BITS) wb = bitsg[(size_t)qrow * NT + t];
    #pragma unroll
    for (int kt = 0; kt < 4; ++kt){
      float p[4];
      #pragma unroll
      for (int j = 0; j < 4; ++j){
        const int bi = kt * 16 + lh * 4 + j;
        int keep;
        if constexpr (BITS) keep = (int)((wb >> bi) & 1ull);
        else                keep = maskg[(size_t)qrow * S_LEN + t * 64 + bi] != 0;
        p[j] = exp2f(keep ? fmaf(acc[kt][j], C_SC, -rlog) : NEGV);
      }
      f32x4 pv; pv[0]=p[0]; pv[1]=p[1]; pv[2]=p[2]; pv[3]=p[3];
      __builtin_nontemporal_store(pv, (f32x4*)&probsb[(size_t)qrow * S_LEN + t * 64 + kt * 16 + lh * 4]);
      short4 ps; ps.x=f2bf(p[0]); ps.y=f2bf(p[1]); ps.z=f2bf(p[2]); ps.w=f2bf(p[3]);
      *(short4*)&Pl[wid * 1024 + swz(ll, kt * 16 + lh * 4)] = ps;
    }
    asm volatile("s_waitcnt lgkmcnt(0)" ::: "memory");
    __builtin_amdgcn_sched_barrier(0);
    #pragma unroll
    for (int k32 = 0; k32 < 2; ++k32){
      const short8v pf = *(const short8v*)&Pl[wid * 1024 + swz(ll, k32 * 32 + lh * 8)];
      #pragma unroll
      for (int dt = 0; dt < 4; ++dt){
        const short8v vf = *(const short8v*)&Vt[swz(dt * 16 + ll, k32 * 32 + lh * 8)];
        o[dt] = __builtin_amdgcn_mfma_f32_16x16x32_bf16(pf, vf, o[dt], 0, 0, 0);
      }
    }
  }

  #pragma unroll
  for (int dt = 0; dt < 4; ++dt)
    #pragma unroll
    for (int j = 0; j < 4; ++j)
      __builtin_nontemporal_store(o[dt][j], &outb[(size_t)(qbase + wid * 16 + lh * 4 + j) * DKC + dt * 16 + ll]);
}

extern "C" void kernel_launch(void* const* d_in, const int* in_sizes, int n_in,
                              void* d_out, int out_size, void* d_ws, size_t ws_size,
                              hipStream_t stream) {
  const float* Q    = (const float*)d_in[0];
  const float* K    = (const float*)d_in[1];
  const float* V    = (const float*)d_in[2];
  const int*   mask = (const int*)d_in[3];

  float* out   = (float*)d_out;
  float* probs = out + (size_t)4 * 16 * 2048 * 64;

  const size_t bitsB = (size_t)S_LEN * S_LEN / 8;          // 512 KiB
  const size_t imgB  = (size_t)64 * NT * 4096 * 2;         // 16 MiB each
  const size_t lnlB  = (size_t)64 * S_LEN * 4;             // 512 KiB
  unsigned long long* bits = (unsigned long long*)d_ws;
  short* Kimg = (short*)((char*)d_ws + bitsB);
  short* Vimg = (short*)((char*)d_ws + bitsB + imgB);
  float* lnl  = (float*)((char*)d_ws + bitsB + 2 * imgB);

  int mode;
  if      (ws_size >= bitsB + 2 * imgB + lnlB) mode = 2;
  else if (ws_size >= bitsB)                   mode = 1;
  else                                         mode = 0;

  if (mode >= 1) maskpack_kernel<<<256, 256, 0, stream>>>(mask, bits);

  if (mode == 2){
    kv_convert<<<64 * NT, 256, 0, stream>>>(K, V, Kimg, Vimg);
    pass_sum<<<64 * 32, 256, 0, stream>>>(Q, bits, Kimg, lnl);
    pass_out<<<64 * 32, 256, 0, stream>>>(Q, bits, Kimg, Vimg, lnl, out, probs);
  } else if (mode == 1){
    attn_fb<1><<<64 * 32, 256, 0, stream>>>(Q, K, V, mask, bits, out, probs);
  } else {
    attn_fb<0><<<64 * 32, 256, 0, stream>>>(Q, K, V, mask, bits, out, probs);
  }
}

// Round 5
// 475.799 us; speedup vs baseline: 1.8430x; 1.0867x over previous
//
#include <hip/hip_runtime.h>
#include <hip/hip_bf16.h>

#define S_LEN 2048
#define NT    32
#define DKC   64
#define NEGV  (-1e9f)
// 0.125 * log2(e): folds the 1/sqrt(64) scale and the exp->exp2 conversion
#define C_SC  0.18033688011112042f

typedef __attribute__((ext_vector_type(8))) short short8v;
typedef __attribute__((ext_vector_type(4))) float f32x4;

__device__ __forceinline__ short f2bf(float f){
  unsigned u = __builtin_bit_cast(unsigned, f);
  u += 0x7fffu + ((u >> 16) & 1u);          // RNE to bf16
  return (short)(u >> 16);
}

// swizzled element index for a [rows][64] bf16 tile (128B rows): XOR bits 3-5
__device__ __forceinline__ int swz(int row, int col){
  return (row * 64 + col) ^ ((row & 7) << 3);
}

// chunked XCD decode: all 32 q-tiles (or k-tiles) of a bh on XCD bh&7,
// with only 2 bh's-worth of image live per XCD at a time.
__device__ __forceinline__ void xcd_decode(int p, int& bh, int& qt){
  const int xcd = p & 7;
  const int n   = p >> 3;
  bh = ((n >> 5) << 3) | xcd;
  qt = n & 31;
}

// ---------------- fallback staging (no-ws path) ----------------
__device__ __forceinline__ void stage_rows_bf16(short* dst, const float* src, int tid){
  const int r  = tid >> 2;
  const int c0 = (tid & 3) * 16;
  const float* p = src + (size_t)r * DKC + c0;
  float4 a0 = *(const float4*)(p);
  float4 a1 = *(const float4*)(p + 4);
  float4 a2 = *(const float4*)(p + 8);
  float4 a3 = *(const float4*)(p + 12);
  short8v s0, s1;
  s0[0]=f2bf(a0.x); s0[1]=f2bf(a0.y); s0[2]=f2bf(a0.z); s0[3]=f2bf(a0.w);
  s0[4]=f2bf(a1.x); s0[5]=f2bf(a1.y); s0[6]=f2bf(a1.z); s0[7]=f2bf(a1.w);
  s1[0]=f2bf(a2.x); s1[1]=f2bf(a2.y); s1[2]=f2bf(a2.z); s1[3]=f2bf(a2.w);
  s1[4]=f2bf(a3.x); s1[5]=f2bf(a3.y); s1[6]=f2bf(a3.z); s1[7]=f2bf(a3.w);
  *(short8v*)&dst[swz(r, c0)]     = s0;
  *(short8v*)&dst[swz(r, c0 + 8)] = s1;
}

__device__ __forceinline__ void stage_vT_bf16(short* dst, const float* src, int tid){
  const int k  = tid >> 4;
  const int d0 = (tid & 15) * 4;
  #pragma unroll
  for (int i = 0; i < 4; ++i){
    const int kk = k + 16 * i;
    const float4 v = *(const float4*)(src + (size_t)kk * DKC + d0);
    dst[swz(d0 + 0, kk)] = f2bf(v.x);
    dst[swz(d0 + 1, kk)] = f2bf(v.y);
    dst[swz(d0 + 2, kk)] = f2bf(v.z);
    dst[swz(d0 + 3, kk)] = f2bf(v.w);
  }
}

// ---------------- precompute kernels ----------------
__global__ void maskpack_kernel(const int* __restrict__ mask, unsigned long long* __restrict__ bits){
  const int w    = blockIdx.x * 4 + (threadIdx.x >> 6);
  const int lane = threadIdx.x & 63;
  for (int i = 0; i < 64; ++i){
    const size_t word = (size_t)w * 64 + i;
    const int v = mask[word * 64 + lane];
    const unsigned long long b = __ballot(v != 0);
    if (lane == 0) bits[word] = b;
  }
}

// Convert one 64x64 tile: K -> bf16 swizzled [r][d], V -> transposed swizzled [d][k],
// Q -> plain row-major bf16. XCD-aligned so writes land in the L2 the passes read.
__global__ __launch_bounds__(256) void kvq_convert(
    const float* __restrict__ Kg, const float* __restrict__ Vg, const float* __restrict__ Qg,
    short* __restrict__ Kimg, short* __restrict__ Vimg, short* __restrict__ Qimg){
  __shared__ float Vf[64][65];
  const int tid = threadIdx.x;
  int bh, t;
  xcd_decode(blockIdx.x, bh, t);
  const size_t tile = (size_t)bh * NT + t;
  const float* Kb = Kg + tile * (64 * 64);
  const float* Vb = Vg + tile * (64 * 64);
  const float* Qb = Qg + tile * (64 * 64);
  short* Ki = Kimg + tile * 4096;
  short* Vi = Vimg + tile * 4096;
  short* Qi = Qimg + tile * 4096;
  // K (swizzled) + Q (plain): direct row conversion
  {
    const int r = tid >> 2, c0 = (tid & 3) * 16;
    const float* p = Kb + (size_t)r * 64 + c0;
    float4 a0 = *(const float4*)(p);
    float4 a1 = *(const float4*)(p + 4);
    float4 a2 = *(const float4*)(p + 8);
    float4 a3 = *(const float4*)(p + 12);
    short8v s0, s1;
    s0[0]=f2bf(a0.x); s0[1]=f2bf(a0.y); s0[2]=f2bf(a0.z); s0[3]=f2bf(a0.w);
    s0[4]=f2bf(a1.x); s0[5]=f2bf(a1.y); s0[6]=f2bf(a1.z); s0[7]=f2bf(a1.w);
    s1[0]=f2bf(a2.x); s1[1]=f2bf(a2.y); s1[2]=f2bf(a2.z); s1[3]=f2bf(a2.w);
    s1[4]=f2bf(a3.x); s1[5]=f2bf(a3.y); s1[6]=f2bf(a3.z); s1[7]=f2bf(a3.w);
    *(short8v*)&Ki[swz(r, c0)]     = s0;
    *(short8v*)&Ki[swz(r, c0 + 8)] = s1;

    const float* q = Qb + (size_t)r * 64 + c0;
    float4 b0 = *(const float4*)(q);
    float4 b1 = *(const float4*)(q + 4);
    float4 b2 = *(const float4*)(q + 8);
    float4 b3 = *(const float4*)(q + 12);
    short8v t0, t1;
    t0[0]=f2bf(b0.x); t0[1]=f2bf(b0.y); t0[2]=f2bf(b0.z); t0[3]=f2bf(b0.w);
    t0[4]=f2bf(b1.x); t0[5]=f2bf(b1.y); t0[6]=f2bf(b1.z); t0[7]=f2bf(b1.w);
    t1[0]=f2bf(b2.x); t1[1]=f2bf(b2.y); t1[2]=f2bf(b2.z); t1[3]=f2bf(b2.w);
    t1[4]=f2bf(b3.x); t1[5]=f2bf(b3.y); t1[6]=f2bf(b3.z); t1[7]=f2bf(b3.w);
    *(short8v*)&Qi[r * 64 + c0]     = t0;
    *(short8v*)&Qi[r * 64 + c0 + 8] = t1;
  }
  // V: LDS transpose
  {
    const int k = tid >> 2, c0 = (tid & 3) * 16;
    const float* p = Vb + (size_t)k * 64 + c0;
    float4 a0 = *(const float4*)(p);
    float4 a1 = *(const float4*)(p + 4);
    float4 a2 = *(const float4*)(p + 8);
    float4 a3 = *(const float4*)(p + 12);
    Vf[k][c0+0]=a0.x; Vf[k][c0+1]=a0.y; Vf[k][c0+2]=a0.z; Vf[k][c0+3]=a0.w;
    Vf[k][c0+4]=a1.x; Vf[k][c0+5]=a1.y; Vf[k][c0+6]=a1.z; Vf[k][c0+7]=a1.w;
    Vf[k][c0+8]=a2.x; Vf[k][c0+9]=a2.y; Vf[k][c0+10]=a2.z; Vf[k][c0+11]=a2.w;
    Vf[k][c0+12]=a3.x; Vf[k][c0+13]=a3.y; Vf[k][c0+14]=a3.z; Vf[k][c0+15]=a3.w;
  }
  __syncthreads();
  {
    const int d = tid >> 2, k0 = (tid & 3) * 16;
    short8v s0, s1;
    #pragma unroll
    for (int i = 0; i < 8; ++i) s0[i] = f2bf(Vf[k0 + i][d]);
    #pragma unroll
    for (int i = 0; i < 8; ++i) s1[i] = f2bf(Vf[k0 + 8 + i][d]);
    *(short8v*)&Vi[swz(d, k0)]     = s0;
    *(short8v*)&Vi[swz(d, k0 + 8)] = s1;
  }
}

// ---------------- split-path helpers ----------------
__device__ __forceinline__ void loadK(short8v (&kf)[8], const short* Kt, int ll, int lh){
  #pragma unroll
  for (int kt = 0; kt < 4; ++kt){
    kf[kt*2+0] = *(const short8v*)(Kt + swz(kt * 16 + ll, lh * 8));
    kf[kt*2+1] = *(const short8v*)(Kt + swz(kt * 16 + ll, 32 + lh * 8));
  }
}

__device__ __forceinline__ float tile_sum(const short8v (&kf)[8], const short8v (&qf)[2],
                                          unsigned long long wb, int lh){
  float s0 = 0.f, s1 = 0.f;
  #pragma unroll
  for (int kt = 0; kt < 4; ++kt){
    f32x4 a = (f32x4){0.f, 0.f, 0.f, 0.f};
    a = __builtin_amdgcn_mfma_f32_16x16x32_bf16(kf[kt*2+0], qf[0], a, 0, 0, 0);
    a = __builtin_amdgcn_mfma_f32_16x16x32_bf16(kf[kt*2+1], qf[1], a, 0, 0, 0);
    #pragma unroll
    for (int j = 0; j < 4; ++j){
      const int bi = kt * 16 + lh * 4 + j;
      const float arg = ((wb >> bi) & 1ull) ? a[j] * C_SC : NEGV;
      if (j & 1) s1 += exp2f(arg); else s0 += exp2f(arg);
    }
  }
  return s0 + s1;
}

// ---------------- PASS 1: denominators (log2 of row sums) ----------------
__global__ __launch_bounds__(256) void pass_sum(
    const short* __restrict__ Qimg, const unsigned long long* __restrict__ bitsg,
    const short* __restrict__ Kimg, float* __restrict__ lnl)
{
  const int tid  = threadIdx.x;
  const int wid  = tid >> 6;
  const int lane = tid & 63;
  const int lh   = lane >> 4;
  const int ll   = lane & 15;

  int bh, qt;
  xcd_decode(blockIdx.x, bh, qt);
  const int qrow = qt * 64 + wid * 16 + ll;

  const short* Qib = Qimg + (size_t)bh * S_LEN * 64;
  const short* Kib = Kimg + (size_t)bh * NT * 4096;

  short8v qf[2];
  qf[0] = *(const short8v*)(Qib + (size_t)qrow * 64 + lh * 8);
  qf[1] = *(const short8v*)(Qib + (size_t)qrow * 64 + 32 + lh * 8);

  float sum = 0.f;
  short8v ka[8], kb[8];
  loadK(ka, Kib, ll, lh);
  for (int tt = 0; tt < NT; tt += 2){
    loadK(kb, Kib + (size_t)(tt + 1) * 4096, ll, lh);
    sum += tile_sum(ka, qf, bitsg[(size_t)qrow * NT + tt], lh);
    const int nx = (tt + 2 < NT) ? tt + 2 : NT - 1;
    loadK(ka, Kib + (size_t)nx * 4096, ll, lh);
    sum += tile_sum(kb, qf, bitsg[(size_t)qrow * NT + tt + 1], lh);
  }
  sum += __shfl_xor(sum, 16, 64);
  sum += __shfl_xor(sum, 32, 64);
  if (lh == 0) lnl[bh * S_LEN + qrow] = __log2f(sum);
}

// ---------------- PASS 2: probs + O = P.V ----------------
__global__ __launch_bounds__(256) void pass_out(
    const short* __restrict__ Qimg, const unsigned long long* __restrict__ bitsg,
    const short* __restrict__ Kimg, const short* __restrict__ Vimg,
    const float* __restrict__ lnl, float* __restrict__ outg, float* __restrict__ probsg)
{
  __shared__ __align__(16) short Pl[4096];   // 2KB per wave, wave-private

  const int tid  = threadIdx.x;
  const int wid  = tid >> 6;
  const int lane = tid & 63;
  const int lh   = lane >> 4;
  const int ll   = lane & 15;

  int bh, qt;
  xcd_decode(blockIdx.x, bh, qt);
  const int qrow = qt * 64 + wid * 16 + ll;

  const short* Qib = Qimg + (size_t)bh * S_LEN * 64;
  const short* Kib = Kimg + (size_t)bh * NT * 4096;
  const short* Vib = Vimg + (size_t)bh * NT * 4096;
  float* outb   = outg   + (size_t)bh * S_LEN * DKC;
  float* probsb = probsg + (size_t)bh * S_LEN * S_LEN;

  short8v qf[2];
  qf[0] = *(const short8v*)(Qib + (size_t)qrow * 64 + lh * 8);
  qf[1] = *(const short8v*)(Qib + (size_t)qrow * 64 + 32 + lh * 8);
  const float rlog = lnl[bh * S_LEN + qrow];

  f32x4 o[4];
  #pragma unroll
  for (int dt = 0; dt < 4; ++dt) o[dt] = (f32x4){0.f, 0.f, 0.f, 0.f};

  for (int t = 0; t < NT; ++t){
    const unsigned long long wb = bitsg[(size_t)qrow * NT + t];
    const short* Vt_ = Vib + (size_t)t * 4096;
    const short* Kt_ = Kib + (size_t)t * 4096;

    // V first: its L2 latency hides under the QK MFMAs + exp chain
    short8v vf[8];
    #pragma unroll
    for (int k32 = 0; k32 < 2; ++k32)
      #pragma unroll
      for (int dt = 0; dt < 4; ++dt)
        vf[k32*4+dt] = *(const short8v*)(Vt_ + swz(dt * 16 + ll, k32 * 32 + lh * 8));

    short8v kf[8];
    loadK(kf, Kt_, ll, lh);

    f32x4 acc[4];
    #pragma unroll
    for (int kt = 0; kt < 4; ++kt){
      f32x4 a = (f32x4){0.f, 0.f, 0.f, 0.f};
      a = __builtin_amdgcn_mfma_f32_16x16x32_bf16(kf[kt*2+0], qf[0], a, 0, 0, 0);
      a = __builtin_amdgcn_mfma_f32_16x16x32_bf16(kf[kt*2+1], qf[1], a, 0, 0, 0);
      acc[kt] = a;
    }

    #pragma unroll
    for (int kt = 0; kt < 4; ++kt){
      float p[4];
      #pragma unroll
      for (int j = 0; j < 4; ++j){
        const int bi = kt * 16 + lh * 4 + j;
        const float arg = ((wb >> bi) & 1ull) ? fmaf(acc[kt][j], C_SC, -rlog) : NEGV;
        p[j] = exp2f(arg);
      }
      f32x4 pv; pv[0]=p[0]; pv[1]=p[1]; pv[2]=p[2]; pv[3]=p[3];
      __builtin_nontemporal_store(pv, (f32x4*)&probsb[(size_t)qrow * S_LEN + t * 64 + kt * 16 + lh * 4]);
      short4 ps; ps.x=f2bf(p[0]); ps.y=f2bf(p[1]); ps.z=f2bf(p[2]); ps.w=f2bf(p[3]);
      *(short4*)&Pl[wid * 1024 + swz(ll, kt * 16 + lh * 4)] = ps;
    }

    // compiler orders the aliasing LDS write->read with its own lgkmcnt
    #pragma unroll
    for (int k32 = 0; k32 < 2; ++k32){
      const short8v pf = *(const short8v*)&Pl[wid * 1024 + swz(ll, k32 * 32 + lh * 8)];
      #pragma unroll
      for (int dt = 0; dt < 4; ++dt)
        o[dt] = __builtin_amdgcn_mfma_f32_16x16x32_bf16(pf, vf[k32*4+dt], o[dt], 0, 0, 0);
    }
  }

  #pragma unroll
  for (int dt = 0; dt < 4; ++dt)
    #pragma unroll
    for (int j = 0; j < 4; ++j)
      __builtin_nontemporal_store(o[dt][j], &outb[(size_t)(qt * 64 + wid * 16 + lh * 4 + j) * DKC + dt * 16 + ll]);
}

// ---------------- fallback: monolithic two-pass with LDS staging ----------------
template<int BITS>
__global__ __launch_bounds__(256) void attn_fb(
    const float* __restrict__ Qg, const float* __restrict__ Kg, const float* __restrict__ Vg,
    const int* __restrict__ maskg, const unsigned long long* __restrict__ bitsg,
    float* __restrict__ outg, float* __restrict__ probsg)
{
  __shared__ __align__(16) short Kl[4096];
  __shared__ __align__(16) short Vt[4096];
  __shared__ __align__(16) short Pl[4096];

  const int tid  = threadIdx.x;
  const int wid  = tid >> 6;
  const int lane = tid & 63;
  const int lh   = lane >> 4;
  const int ll   = lane & 15;

  const int qt    = blockIdx.x & 31;
  const int bh    = blockIdx.x >> 5;
  const int qbase = qt * 64;
  const int qrow  = qbase + wid * 16 + ll;

  const float* Qb = Qg + (size_t)bh * S_LEN * DKC;
  const float* Kb = Kg + (size_t)bh * S_LEN * DKC;
  const float* Vb = Vg + (size_t)bh * S_LEN * DKC;
  float* outb   = outg   + (size_t)bh * S_LEN * DKC;
  float* probsb = probsg + (size_t)bh * S_LEN * S_LEN;

  short8v qf[2];
  #pragma unroll
  for (int h = 0; h < 2; ++h){
    const float4 a = *(const float4*)(Qb + (size_t)qrow * DKC + h * 32 + lh * 8);
    const float4 b = *(const float4*)(Qb + (size_t)qrow * DKC + h * 32 + lh * 8 + 4);
    short8v t;
    t[0]=f2bf(a.x); t[1]=f2bf(a.y); t[2]=f2bf(a.z); t[3]=f2bf(a.w);
    t[4]=f2bf(b.x); t[5]=f2bf(b.y); t[6]=f2bf(b.z); t[7]=f2bf(b.w);
    qf[h] = t;
  }

  float sum = 0.f;
  for (int t = 0; t < NT; ++t){
    __syncthreads();
    stage_rows_bf16(Kl, Kb + (size_t)t * 64 * DKC, tid);
    __syncthreads();
    unsigned long long wb = 0;
    if constexpr (BITS) wb = bitsg[(size_t)qrow * NT + t];
    #pragma unroll
    for (int kt = 0; kt < 4; ++kt){
      const short8v kf0 = *(const short8v*)&Kl[swz(kt * 16 + ll, lh * 8)];
      const short8v kf1 = *(const short8v*)&Kl[swz(kt * 16 + ll, 32 + lh * 8)];
      f32x4 a = (f32x4){0.f, 0.f, 0.f, 0.f};
      a = __builtin_amdgcn_mfma_f32_16x16x32_bf16(kf0, qf[0], a, 0, 0, 0);
      a = __builtin_amdgcn_mfma_f32_16x16x32_bf16(kf1, qf[1], a, 0, 0, 0);
      #pragma unroll
      for (int j = 0; j < 4; ++j){
        const int bi = kt * 16 + lh * 4 + j;
        int keep;
        if constexpr (BITS) keep = (int)((wb >> bi) & 1ull);
        else                keep = maskg[(size_t)qrow * S_LEN + t * 64 + bi] != 0;
        sum += exp2f(keep ? a[j] * C_SC : NEGV);
      }
    }
  }
  sum += __shfl_xor(sum, 16, 64);
  sum += __shfl_xor(sum, 32, 64);
  const float rlog = __log2f(sum);

  f32x4 o[4];
  #pragma unroll
  for (int dt = 0; dt < 4; ++dt) o[dt] = (f32x4){0.f, 0.f, 0.f, 0.f};

  for (int t = 0; t < NT; ++t){
    __syncthreads();
    stage_rows_bf16(Kl, Kb + (size_t)t * 64 * DKC, tid);
    stage_vT_bf16 (Vt, Vb + (size_t)t * 64 * DKC, tid);
    __syncthreads();
    f32x4 acc[4];
    #pragma unroll
    for (int kt = 0; kt < 4; ++kt){
      const short8v kf0 = *(const short8v*)&Kl[swz(kt * 16 + ll, lh * 8)];
      const short8v kf1 = *(const short8v*)&Kl[swz(kt * 16 + ll, 32 + lh * 8)];
      f32x4 a = (f32x4){0.f, 0.f, 0.f, 0.f};
      a = __builtin_amdgcn_mfma_f32_16x16x32_bf16(kf0, qf[0], a, 0, 0, 0);
      a = __builtin_amdgcn_mfma_f32_16x16x32_bf16(kf1, qf[1], a, 0, 0, 0);
      acc[kt] = a;
    }
    unsigned long long wb = 0;
    if constexpr (BITS) wb = bitsg[(size_t)qrow * NT + t];
    #pragma unroll
    for (int kt = 0; kt < 4; ++kt){
      float p[4];
      #pragma unroll
      for (int j = 0; j < 4; ++j){
        const int bi = kt * 16 + lh * 4 + j;
        int keep;
        if constexpr (BITS) keep = (int)((wb >> bi) & 1ull);
        else                keep = maskg[(size_t)qrow * S_LEN + t * 64 + bi] != 0;
        p[j] = exp2f(keep ? fmaf(acc[kt][j], C_SC, -rlog) : NEGV);
      }
      f32x4 pv; pv[0]=p[0]; pv[1]=p[1]; pv[2]=p[2]; pv[3]=p[3];
      __builtin_nontemporal_store(pv, (f32x4*)&probsb[(size_t)qrow * S_LEN + t * 64 + kt * 16 + lh * 4]);
      short4 ps; ps.x=f2bf(p[0]); ps.y=f2bf(p[1]); ps.z=f2bf(p[2]); ps.w=f2bf(p[3]);
      *(short4*)&Pl[wid * 1024 + swz(ll, kt * 16 + lh * 4)] = ps;
    }
    asm volatile("s_waitcnt lgkmcnt(0)" ::: "memory");
    __builtin_amdgcn_sched_barrier(0);
    #pragma unroll
    for (int k32 = 0; k32 < 2; ++k32){
      const short8v pf = *(const short8v*)&Pl[wid * 1024 + swz(ll, k32 * 32 + lh * 8)];
      #pragma unroll
      for (int dt = 0; dt < 4; ++dt){
        const short8v vf = *(const short8v*)&Vt[swz(dt * 16 + ll, k32 * 32 + lh * 8)];
        o[dt] = __builtin_amdgcn_mfma_f32_16x16x32_bf16(pf, vf, o[dt], 0, 0, 0);
      }
    }
  }

  #pragma unroll
  for (int dt = 0; dt < 4; ++dt)
    #pragma unroll
    for (int j = 0; j < 4; ++j)
      __builtin_nontemporal_store(o[dt][j], &outb[(size_t)(qbase + wid * 16 + lh * 4 + j) * DKC + dt * 16 + ll]);
}

extern "C" void kernel_launch(void* const* d_in, const int* in_sizes, int n_in,
                              void* d_out, int out_size, void* d_ws, size_t ws_size,
                              hipStream_t stream) {
  const float* Q    = (const float*)d_in[0];
  const float* K    = (const float*)d_in[1];
  const float* V    = (const float*)d_in[2];
  const int*   mask = (const int*)d_in[3];

  float* out   = (float*)d_out;
  float* probs = out + (size_t)4 * 16 * 2048 * 64;

  const size_t bitsB = (size_t)S_LEN * S_LEN / 8;          // 512 KiB
  const size_t imgB  = (size_t)64 * NT * 4096 * 2;         // 16 MiB each
  const size_t lnlB  = (size_t)64 * S_LEN * 4;             // 512 KiB
  unsigned long long* bits = (unsigned long long*)d_ws;
  short* Kimg = (short*)((char*)d_ws + bitsB);
  short* Vimg = (short*)((char*)d_ws + bitsB + imgB);
  short* Qimg = (short*)((char*)d_ws + bitsB + 2 * imgB);
  float* lnl  = (float*)((char*)d_ws + bitsB + 3 * imgB);

  int mode;
  if      (ws_size >= bitsB + 3 * imgB + lnlB) mode = 2;
  else if (ws_size >= bitsB)                   mode = 1;
  else                                         mode = 0;

  if (mode >= 1) maskpack_kernel<<<256, 256, 0, stream>>>(mask, bits);

  if (mode == 2){
    kvq_convert<<<64 * NT, 256, 0, stream>>>(K, V, Q, Kimg, Vimg, Qimg);
    pass_sum<<<64 * 32, 256, 0, stream>>>(Qimg, bits, Kimg, lnl);
    pass_out<<<64 * 32, 256, 0, stream>>>(Qimg, bits, Kimg, Vimg, lnl, out, probs);
  } else if (mode == 1){
    attn_fb<1><<<64 * 32, 256, 0, stream>>>(Q, K, V, mask, bits, out, probs);
  } else {
    attn_fb<0><<<64 * 32, 256, 0, stream>>>(Q, K, V, mask, bits, out, probs);
  }
}